// Round 4
// baseline (1022.320 us; speedup 1.0000x reference)
//
#include <hip/hip_runtime.h>
#include <hip/hip_bf16.h>
#include <hip/hip_fp16.h>

// Bidirectional char-LSTM + masked max-pool, fused into ONE kernel.
// 512 blocks = (batch=256) x (dir=2); each block runs one chain of T=512 steps.
// 1024 threads/block: each gate row (4H=512) is split across 2 threads
// (kseg = tid>>9, wave-uniform), each holding 46 packed-fp16x2 u32 weights in
// VGPRs -- sized to fit the 64-VGPR budget the allocator insists on (R1-R3:
// 92+ u32/thread spilled 80 MB to scratch at VGPR_Count=64).
// Partial dots combine through part[2][512] in LDS.

#define TT 512
#define DD 50
#define HH 128
#define KH 184    // padded half count of [x(50) | h(128) | pad(6)]
#define KSEG 92   // halves per K-segment (46 u32)

typedef _Float16 h2_t __attribute__((ext_vector_type(2)));
typedef unsigned int u32;

static __device__ __forceinline__ u32 packh2(float lo, float hi) {
    union { h2_t h; u32 u; } cv;
    cv.h.x = (_Float16)lo;
    cv.h.y = (_Float16)hi;
    return cv.u;
}

static __device__ __forceinline__ float dot2(u32 a, u32 b, float c) {
    union { u32 u; h2_t h; } ca, cb;
    ca.u = a; cb.u = b;
#if __has_builtin(__builtin_amdgcn_fdot2)
    return __builtin_amdgcn_fdot2(ca.h, cb.h, c, false);
#else
    return c + (float)ca.h.x * (float)cb.h.x + (float)ca.h.y * (float)cb.h.y;
#endif
}

static __device__ __forceinline__ float fexp(float x) {
#if __has_builtin(__builtin_amdgcn_exp2f)
    return __builtin_amdgcn_exp2f(x * 1.44269504088896341f);
#else
    return __expf(x);
#endif
}
static __device__ __forceinline__ float frcp(float x) {
#if __has_builtin(__builtin_amdgcn_rcpf)
    return __builtin_amdgcn_rcpf(x);
#else
    return 1.0f / x;
#endif
}
static __device__ __forceinline__ float sigf(float x) {
    return frcp(1.f + fexp(-x));
}
static __device__ __forceinline__ float tanhf_(float x) {
    return 1.f - 2.f * frcp(fexp(2.f * x) + 1.f);
}

__global__ __launch_bounds__(1024)
void bilstm_maxpool_kernel(const int* __restrict__ idx,
                           const float* __restrict__ masks,
                           const float* __restrict__ emb,
                           const float* __restrict__ Wih_f, const float* __restrict__ Whh_f,
                           const float* __restrict__ bih_f, const float* __restrict__ bhh_f,
                           const float* __restrict__ Wih_b, const float* __restrict__ Whh_b,
                           const float* __restrict__ bih_b, const float* __restrict__ bhh_b,
                           float* __restrict__ out)
{
    __shared__ __align__(16) _Float16 hx[2][KH];  // [x(50) | h(128) | pad(6)], x2 dbuf
    __shared__ float part[2][4 * HH];             // K-split partial gate sums
    __shared__ int   idx_s[TT];
    __shared__ float pen_s[TT];

    const int tid  = threadIdx.x;
    const int r    = tid & 511;       // gate row 0..511
    const int kseg = tid >> 9;        // 0 or 1: which half of K (wave-uniform)
    const int d    = blockIdx.x & 1;  // 0=fwd, 1=bwd
    const int b    = blockIdx.x >> 1;
    const int rev  = d;

    const float* Wih = d ? Wih_b : Wih_f;
    const float* Whh = d ? Whh_b : Whh_f;
    const float* bih = d ? bih_b : bih_f;
    const float* bhh = d ? bhh_b : bhh_f;

    // ---- preload idx + mask-penalty rows into LDS; zero hx (h0 = 0, pads = 0)
    if (tid < TT) {
        idx_s[tid] = idx[b * TT + tid];
        pen_s[tid] = (1.0f - masks[b * TT + tid]) * 1e8f;
    }
    {
        _Float16* p = &hx[0][0];
        for (int k = tid; k < 2 * KH; k += 1024) p[k] = (_Float16)0.f;
    }

    // ---- per-thread weights: 46 u32 = halves [kseg*92, kseg*92+92) of row r
    u32 w[46];
#pragma unroll
    for (int k = 0; k < 46; ++k) {
        const int kh = kseg * KSEG + 2 * k;   // even half index
        float x0, x1;
        if (kh < 50) {                        // Wih part: halves 0..49 (50 even: no straddle)
            x0 = Wih[r * DD + kh]; x1 = Wih[r * DD + kh + 1];
        } else if (kh < 178) {                // Whh part: halves 50..177
            x0 = Whh[r * HH + kh - 50]; x1 = Whh[r * HH + kh - 49];
        } else {                              // pad
            x0 = x1 = 0.f;
        }
        w[k] = packh2(x0, x1);
    }
    const float bias = (kseg == 0) ? (bih[r] + bhh[r]) : 0.f;

    __syncthreads();

    // ---- first x tile into hx[0]: threads 128..177 handle the 50 x-halves
    const int jj = tid - HH;                  // 0..49 for the x-loader threads
    const bool is_x = (jj >= 0 && jj < DD);
    if (is_x) {
        const int t0 = rev ? (TT - 1) : 0;
        hx[0][jj] = (_Float16)emb[idx_s[t0] * DD + jj];
    }
    __syncthreads();

    float c0 = 0.f, rm0 = -3e38f;
    int cur = 0;

    for (int s = 0; s < TT; ++s) {
        const int t = rev ? (TT - 1 - s) : s;

        // prefetch next step's embedding value (latency hidden under the dots)
        float e = 0.f;
        const bool pf = is_x && (s + 1 < TT);
        if (pf) {
            const int t1 = rev ? (TT - 2 - s) : (s + 1);
            e = emb[idx_s[t1] * DD + jj];
        }

        // ---- phase A: partial gate dot, 46 half2 per thread, 4 accumulators
        // All lanes of a wave read the same LDS address -> broadcast, no conflict.
        const uint2* hv = (const uint2*)(&hx[cur][0]) + kseg * 23;
        float a0 = bias, a1 = 0.f, a2 = 0.f, a3 = 0.f;
#pragma unroll
        for (int q = 0; q < 11; ++q) {
            const uint2 u = hv[2 * q];
            const uint2 v = hv[2 * q + 1];
            a0 = dot2(w[4 * q + 0], u.x, a0);
            a1 = dot2(w[4 * q + 1], u.y, a1);
            a2 = dot2(w[4 * q + 2], v.x, a2);
            a3 = dot2(w[4 * q + 3], v.y, a3);
        }
        {
            const uint2 u = hv[22];
            a0 = dot2(w[44], u.x, a0);
            a1 = dot2(w[45], u.y, a1);
        }
        part[kseg][r] = (a0 + a1) + (a2 + a3);
        __syncthreads();

        // ---- phase B: threads 0..127 update c/h for 1 hidden dim each;
        //      threads 128..177 write the prefetched x into the other buffer
        if (tid < HH) {
            const float i0 = part[0][tid]          + part[1][tid];
            const float f0 = part[0][HH + tid]     + part[1][HH + tid];
            const float g0 = part[0][2 * HH + tid] + part[1][2 * HH + tid];
            const float o0 = part[0][3 * HH + tid] + part[1][3 * HH + tid];
            c0 = sigf(f0) * c0 + sigf(i0) * tanhf_(g0);
            const float h0 = sigf(o0) * tanhf_(c0);
            rm0 = fmaxf(rm0, h0 - pen_s[t]);
            hx[cur ^ 1][DD + tid] = (_Float16)h0;
        } else if (pf) {
            hx[cur ^ 1][jj] = (_Float16)e;
        }
        __syncthreads();
        cur ^= 1;
    }

    if (tid < HH) {
        out[b * 256 + d * HH + tid] = rm0;
    }
}

extern "C" void kernel_launch(void* const* d_in, const int* in_sizes, int n_in,
                              void* d_out, int out_size, void* d_ws, size_t ws_size,
                              hipStream_t stream) {
    const int*   idx   = (const int*)d_in[0];
    const float* masks = (const float*)d_in[1];
    const float* emb   = (const float*)d_in[2];
    const float* Wih_f = (const float*)d_in[3];
    const float* Whh_f = (const float*)d_in[4];
    const float* bih_f = (const float*)d_in[5];
    const float* bhh_f = (const float*)d_in[6];
    const float* Wih_b = (const float*)d_in[7];
    const float* Whh_b = (const float*)d_in[8];
    const float* bih_b = (const float*)d_in[9];
    const float* bhh_b = (const float*)d_in[10];
    float* out = (float*)d_out;

    bilstm_maxpool_kernel<<<dim3(512), dim3(1024), 0, stream>>>(
        idx, masks, emb,
        Wih_f, Whh_f, bih_f, bhh_f,
        Wih_b, Whh_b, bih_b, bhh_b,
        out);
}

// Round 5
// 837.173 us; speedup vs baseline: 1.2212x; 1.2212x over previous
//
#include <hip/hip_runtime.h>
#include <hip/hip_bf16.h>
#include <hip/hip_fp16.h>

// Bidirectional char-LSTM + masked max-pool, fused into ONE kernel.
// 512 blocks = (batch=256) x (dir=2); each block runs one chain of T=512 steps.
// 512 threads/block (8 waves): each thread owns ONE full gate row (of 4H=512)
// as 96 packed-fp16x2 u32 in VGPRs. amdgpu_num_vgpr(128) pins the register
// budget (R2/R3: launch_bounds/waves_per_eu caps were ignored and the
// allocator chose 64 -> 80 MB scratch spill; R4's spill-free 1024-thread
// variant hit the 16-wave co-residency cliff: 1 block/CU, exposed barriers).
// At 128 VGPR: 4 waves/SIMD x 2 blocks/CU = 16 waves/CU, barriers of one
// block hidden under compute of the other.
// hx operand = [x(50)|h(128)|pad(14)] fp16 in LDS, read as 24 broadcast
// ds_read_b128; dot via v_dot2_f32_f16 (f32 accumulate).

#define TT 512
#define DD 50
#define HH 128
#define KH 192    // padded half count (16B-aligned: 24 uint4)
#define KP4 24    // uint4 groups per row

typedef _Float16 h2_t __attribute__((ext_vector_type(2)));
typedef unsigned int u32;

static __device__ __forceinline__ u32 packh2(float lo, float hi) {
    union { h2_t h; u32 u; } cv;
    cv.h.x = (_Float16)lo;
    cv.h.y = (_Float16)hi;
    return cv.u;
}

static __device__ __forceinline__ float dot2(u32 a, u32 b, float c) {
    union { u32 u; h2_t h; } ca, cb;
    ca.u = a; cb.u = b;
#if __has_builtin(__builtin_amdgcn_fdot2)
    return __builtin_amdgcn_fdot2(ca.h, cb.h, c, false);
#else
    return c + (float)ca.h.x * (float)cb.h.x + (float)ca.h.y * (float)cb.h.y;
#endif
}

static __device__ __forceinline__ float fexp(float x) {
#if __has_builtin(__builtin_amdgcn_exp2f)
    return __builtin_amdgcn_exp2f(x * 1.44269504088896341f);
#else
    return __expf(x);
#endif
}
static __device__ __forceinline__ float frcp(float x) {
#if __has_builtin(__builtin_amdgcn_rcpf)
    return __builtin_amdgcn_rcpf(x);
#else
    return 1.0f / x;
#endif
}
static __device__ __forceinline__ float sigf(float x) {
    return frcp(1.f + fexp(-x));
}
static __device__ __forceinline__ float tanhf_(float x) {
    return 1.f - 2.f * frcp(fexp(2.f * x) + 1.f);
}

__global__ __attribute__((amdgpu_flat_work_group_size(512, 512),
                          amdgpu_num_vgpr(128)))
void bilstm_maxpool_kernel(const int* __restrict__ idx,
                           const float* __restrict__ masks,
                           const float* __restrict__ emb,
                           const float* __restrict__ Wih_f, const float* __restrict__ Whh_f,
                           const float* __restrict__ bih_f, const float* __restrict__ bhh_f,
                           const float* __restrict__ Wih_b, const float* __restrict__ Whh_b,
                           const float* __restrict__ bih_b, const float* __restrict__ bhh_b,
                           float* __restrict__ out)
{
    __shared__ __align__(16) _Float16 hx[2][KH];  // [x(50) | h(128) | pad(14)], x2 dbuf
    __shared__ float gates[4 * HH];
    __shared__ int   idx_s[TT];
    __shared__ float pen_s[TT];

    const int tid = threadIdx.x;
    const int d   = blockIdx.x & 1;   // 0=fwd, 1=bwd
    const int b   = blockIdx.x >> 1;
    const int rev = d;

    const float* Wih = d ? Wih_b : Wih_f;
    const float* Whh = d ? Whh_b : Whh_f;
    const float* bih = d ? bih_b : bih_f;
    const float* bhh = d ? bhh_b : bhh_f;

    // ---- preload idx + mask-penalty rows into LDS; zero hx (h0 = 0, pads = 0)
    if (tid < TT) {
        idx_s[tid] = idx[b * TT + tid];
        pen_s[tid] = (1.0f - masks[b * TT + tid]) * 1e8f;
    }
    {
        _Float16* p = &hx[0][0];
        for (int k = tid; k < 2 * KH; k += 512) p[k] = (_Float16)0.f;
    }

    // ---- per-thread weights: ONE gate row r = tid, 96 packed half2
    const int r = tid;
    u32 w[4 * KP4];
#pragma unroll
    for (int k = 0; k < 4 * KP4; ++k) {
        const int kh = 2 * k;
        float x0, x1;
        if (kh < 50) {                        // Wih part: halves 0..49
            x0 = Wih[r * DD + kh]; x1 = Wih[r * DD + kh + 1];
        } else if (kh < 178) {                // Whh part: halves 50..177
            x0 = Whh[r * HH + kh - 50]; x1 = Whh[r * HH + kh - 49];
        } else {                              // pad halves 178..191
            x0 = x1 = 0.f;
        }
        w[k] = packh2(x0, x1);
    }
    const float bias = bih[r] + bhh[r];

    __syncthreads();

    // ---- first x tile into hx[0]: threads 128..177 handle the 50 x-halves
    const int jj = tid - HH;                  // 0..49 for the x-loader threads
    const bool is_x = (jj >= 0 && jj < DD);
    if (is_x) {
        const int t0 = rev ? (TT - 1) : 0;
        hx[0][jj] = (_Float16)emb[idx_s[t0] * DD + jj];
    }
    __syncthreads();

    float c0 = 0.f, rm0 = -3e38f;
    int cur = 0;

    for (int s = 0; s < TT; ++s) {
        const int t = rev ? (TT - 1 - s) : s;

        // prefetch next step's embedding value (latency hidden under the dots)
        float e = 0.f;
        const bool pf = is_x && (s + 1 < TT);
        if (pf) {
            const int t1 = rev ? (TT - 2 - s) : (s + 1);
            e = emb[idx_s[t1] * DD + jj];
        }

        // ---- phase A: 1 gate dot per thread, K = 192 halves, 4 accumulators.
        // All lanes read the same LDS address -> broadcast ds_read_b128.
        float a0 = bias, a1 = 0.f, a2 = 0.f, a3 = 0.f;
        const uint4* hv = (const uint4*)(&hx[cur][0]);
#pragma unroll
        for (int q = 0; q < KP4; ++q) {
            const uint4 v = hv[q];
            a0 = dot2(w[4*q+0], v.x, a0);
            a1 = dot2(w[4*q+1], v.y, a1);
            a2 = dot2(w[4*q+2], v.z, a2);
            a3 = dot2(w[4*q+3], v.w, a3);
        }
        gates[r] = (a0 + a1) + (a2 + a3);
        __syncthreads();

        // ---- phase B: threads 0..127 update c/h for 1 hidden dim each;
        //      threads 128..177 write the prefetched x into the other buffer
        if (tid < HH) {
            const float i0 = gates[tid];
            const float f0 = gates[HH + tid];
            const float g0 = gates[2 * HH + tid];
            const float o0 = gates[3 * HH + tid];
            c0 = sigf(f0) * c0 + sigf(i0) * tanhf_(g0);
            const float h0 = sigf(o0) * tanhf_(c0);
            rm0 = fmaxf(rm0, h0 - pen_s[t]);
            hx[cur ^ 1][DD + tid] = (_Float16)h0;
        } else if (pf) {
            hx[cur ^ 1][jj] = (_Float16)e;
        }
        __syncthreads();
        cur ^= 1;
    }

    if (tid < HH) {
        out[b * 256 + d * HH + tid] = rm0;
    }
}

extern "C" void kernel_launch(void* const* d_in, const int* in_sizes, int n_in,
                              void* d_out, int out_size, void* d_ws, size_t ws_size,
                              hipStream_t stream) {
    const int*   idx   = (const int*)d_in[0];
    const float* masks = (const float*)d_in[1];
    const float* emb   = (const float*)d_in[2];
    const float* Wih_f = (const float*)d_in[3];
    const float* Whh_f = (const float*)d_in[4];
    const float* bih_f = (const float*)d_in[5];
    const float* bhh_f = (const float*)d_in[6];
    const float* Wih_b = (const float*)d_in[7];
    const float* Whh_b = (const float*)d_in[8];
    const float* bih_b = (const float*)d_in[9];
    const float* bhh_b = (const float*)d_in[10];
    float* out = (float*)d_out;

    bilstm_maxpool_kernel<<<dim3(512), dim3(512), 0, stream>>>(
        idx, masks, emb,
        Wih_f, Whh_f, bih_f, bhh_f,
        Wih_b, Whh_b, bih_b, bhh_b,
        out);
}

// Round 7
// 582.237 us; speedup vs baseline: 1.7558x; 1.4379x over previous
//
#include <hip/hip_runtime.h>
#include <hip/hip_fp16.h>

// Bidirectional char-LSTM + masked max-pool via MFMA.
// 32 blocks = 2 dirs x 16 chain-groups; each block runs 16 chains (same
// direction -> shared weights) for T=512 steps.
// Per step: D[16 chains][512 gates] = A[16][192] * B[192][512] with
// mfma_f32_16x16x32_f16. B (weights, fp16) lives in VGPRs as 24 fragments
// per wave (wave w owns gate cols {w*16..+15} + 128/256/384 offsets, so
// i,f,g,o for a hidden dim land in the SAME lane -> activation, c-state and
// running max stay in registers; ONE barrier per step).
// A = [x(50)|pad(14)|h(128)] fp16 in LDS, XOR-slot swizzled, double-buffered.
// R1-R5 lesson: per-thread-row GEMV is LDS-broadcast-bound (~1900cyc/step);
// MFMA cuts LDS reads 8x and removes the gates LDS round-trip.

#define TT 512
#define CH 16      // chains per block
#define ROWB 384   // bytes per A row (192 halves)

typedef _Float16 f16;
typedef _Float16 f16x8 __attribute__((ext_vector_type(8)));
typedef float f32x4 __attribute__((ext_vector_type(4)));
typedef unsigned int u32;
typedef unsigned short u16;

static __device__ __forceinline__ u32 packh2(float lo, float hi) {
    union { struct { f16 x, y; } h; u32 u; } cv;
    cv.h.x = (f16)lo; cv.h.y = (f16)hi;
    return cv.u;
}
static __device__ __forceinline__ u16 f16bits(float v) {
    union { f16 h; u16 u; } cv; cv.h = (f16)v; return cv.u;
}
static __device__ __forceinline__ float fexp(float x) {
    return __builtin_amdgcn_exp2f(x * 1.44269504088896341f);
}
static __device__ __forceinline__ float frcp(float x) {
    return __builtin_amdgcn_rcpf(x);
}
static __device__ __forceinline__ float sigf(float x) {
    return frcp(1.f + fexp(-x));
}
static __device__ __forceinline__ float tanhf_(float x) {
    return 1.f - 2.f * frcp(fexp(2.f * x) + 1.f);
}

__global__ __attribute__((amdgpu_flat_work_group_size(512, 512),
                          amdgpu_waves_per_eu(2, 2)))
void bilstm_mfma_kernel(const int* __restrict__ idx,
                        const float* __restrict__ masks,
                        const float* __restrict__ emb,
                        const float* __restrict__ Wih_f, const float* __restrict__ Whh_f,
                        const float* __restrict__ bih_f, const float* __restrict__ bhh_f,
                        const float* __restrict__ Wih_b, const float* __restrict__ Whh_b,
                        const float* __restrict__ bih_b, const float* __restrict__ bhh_b,
                        float* __restrict__ out)
{
    __shared__ __align__(16) unsigned char Abuf[2][CH * ROWB]; // 12 KB
    __shared__ u16 idx16[CH * TT];                             // 16 KB
    __shared__ u32 mbits[TT];                                  // 2 KB

    const int tid  = threadIdx.x;
    const int lane = tid & 63;
    const int wv   = tid >> 6;        // wave 0..7
    const int l15  = lane & 15;
    const int c4   = lane >> 4;       // 0..3 (chain group)
    const int d    = blockIdx.x >> 4; // 0 fwd, 1 bwd
    const int g    = blockIdx.x & 15;
    const int b0   = g * CH;
    const int rev  = d;

    const float* Wih = d ? Wih_b : Wih_f;
    const float* Whh = d ? Whh_b : Whh_f;
    const float* bih = d ? bih_b : bih_f;
    const float* bhh = d ? bhh_b : bhh_f;

    // ---- init: idx (u16), mask bitmasks, zero A buffers
    for (int i = tid; i < CH * TT; i += 512) {
        const int m = i >> 9, t = i & 511;
        idx16[i] = (u16)idx[(b0 + m) * TT + t];
    }
    if (tid < TT) {
        u32 mb = 0;
        for (int m = 0; m < CH; ++m)
            mb |= (masks[(b0 + m) * TT + tid] != 0.f ? 1u : 0u) << m;
        mbits[tid] = mb;
    }
    for (int i = tid; i < 2 * CH * ROWB / 4; i += 512)
        ((u32*)Abuf)[i] = 0u;

    // ---- B fragments in VGPRs: w[kt][nt], kt=K-tile 0..5, nt=gate 0..3
    // B[k][n]: k<50 -> Wih[n][k]; 50<=k<64 -> 0; k>=64 -> Whh[n][k-64].
    // Lane holds B[kt*32 + c4*8 + j][ nt*128 + wv*16 + l15 ], j=0..7.
    f16x8 w[6][4];
    float bias_v[4];
#pragma unroll
    for (int nt = 0; nt < 4; ++nt) {
        const int n = nt * 128 + wv * 16 + l15;
        bias_v[nt] = bih[n] + bhh[n];
        // kt = 0: k = c4*8 + j  (all < 32 < 50) -> Wih, float2 x4
#pragma unroll
        for (int jj = 0; jj < 4; ++jj) {
            const float2 e = *(const float2*)(Wih + n * 50 + c4 * 8 + jj * 2);
            w[0][nt][2 * jj]     = (f16)e.x;
            w[0][nt][2 * jj + 1] = (f16)e.y;
        }
        // kt = 1: k = 32 + c4*8 + j, real iff k < 50 (lane-predicated)
#pragma unroll
        for (int j = 0; j < 8; ++j) {
            const int k = 32 + c4 * 8 + j;
            float v = 0.f;
            if (k < 50) v = Wih[n * 50 + k];
            w[1][nt][j] = (f16)v;
        }
        // kt = 2..5: k >= 64 -> Whh, float4 x2 (16B aligned)
#pragma unroll
        for (int kt = 2; kt < 6; ++kt) {
            const int kh = (kt - 2) * 32 + c4 * 8;
            const float4 e0 = *(const float4*)(Whh + n * 128 + kh);
            const float4 e1 = *(const float4*)(Whh + n * 128 + kh + 4);
            w[kt][nt][0] = (f16)e0.x; w[kt][nt][1] = (f16)e0.y;
            w[kt][nt][2] = (f16)e0.z; w[kt][nt][3] = (f16)e0.w;
            w[kt][nt][4] = (f16)e1.x; w[kt][nt][5] = (f16)e1.y;
            w[kt][nt][6] = (f16)e1.z; w[kt][nt][7] = (f16)e1.w;
        }
    }

    // ---- x for step 0: threads 0..399, 25 per chain, float2 (2 halves) each
    const int pm = tid / 25;          // chain
    const int ps = tid % 25;          // half-pair index (k = 2*ps, 2*ps+1)
    if (tid < 400) {
        const int t0  = rev ? (TT - 1) : 0;
        const int row = idx16[pm * TT + t0];
        const float2 e = *(const float2*)(emb + row * 50 + ps * 2);
        const int bk = ps * 4, slot = bk >> 4, within = bk & 15;
        *(u32*)(&Abuf[0][pm * ROWB + (((slot) ^ (pm & 7)) << 4) + within]) =
            packh2(e.x, e.y);
    }
    __syncthreads();

    float cst[4] = {0.f, 0.f, 0.f, 0.f};
    float rm[4]  = {-3e38f, -3e38f, -3e38f, -3e38f};

    const int hd      = wv * 16 + l15;          // hidden dim owned by lane
    const int hslot   = (128 + hd * 2) >> 4;    // A-row slot of h[hd]
    const int hwithin = (hd * 2) & 15;

    for (int s = 0; s < TT; ++s) {
        const int cur = s & 1;
        const int t   = rev ? (TT - 1 - s) : s;

        // prefetch next step's x row-pair (hidden under MFMA)
        float2 e;
        const bool pf = (tid < 400) && (s + 1 < TT);
        if (pf) {
            const int t1  = rev ? (TT - 2 - s) : (s + 1);
            const int row = idx16[pm * TT + t1];
            e = *(const float2*)(emb + row * 50 + ps * 2);
        }

        // ---- MFMA: acc[nt] = bias + A(16x192) * B(192x[nt slice])
        const unsigned char* ab = &Abuf[cur][0];
        f32x4 a0 = {bias_v[0], bias_v[0], bias_v[0], bias_v[0]};
        f32x4 a1 = {bias_v[1], bias_v[1], bias_v[1], bias_v[1]};
        f32x4 a2 = {bias_v[2], bias_v[2], bias_v[2], bias_v[2]};
        f32x4 a3 = {bias_v[3], bias_v[3], bias_v[3], bias_v[3]};
#pragma unroll
        for (int kt = 0; kt < 6; ++kt) {
            const f16x8 af = *(const f16x8*)(
                ab + l15 * ROWB + ((((kt << 2) | c4) ^ (l15 & 7)) << 4));
            a0 = __builtin_amdgcn_mfma_f32_16x16x32_f16(af, w[kt][0], a0, 0, 0, 0);
            a1 = __builtin_amdgcn_mfma_f32_16x16x32_f16(af, w[kt][1], a1, 0, 0, 0);
            a2 = __builtin_amdgcn_mfma_f32_16x16x32_f16(af, w[kt][2], a2, 0, 0, 0);
            a3 = __builtin_amdgcn_mfma_f32_16x16x32_f16(af, w[kt][3], a3, 0, 0, 0);
        }

        // ---- in-lane LSTM update for 4 chains (m = c4*4+q), dim hd
        const u32 mb = mbits[t];
        unsigned char* nb = &Abuf[cur ^ 1][0];
#pragma unroll
        for (int q = 0; q < 4; ++q) {
            const float iv = a0[q], fv = a1[q], gv = a2[q], ov = a3[q];
            const float cc = sigf(fv) * cst[q] + sigf(iv) * tanhf_(gv);
            cst[q] = cc;
            const float hh = sigf(ov) * tanhf_(cc);
            const int m = c4 * 4 + q;
            const float pen = ((mb >> m) & 1u) ? 0.f : 1e8f;
            rm[q] = fmaxf(rm[q], hh - pen);
            *(u16*)(nb + m * ROWB + ((hslot ^ (m & 7)) << 4) + hwithin) =
                f16bits(hh);
        }
        if (pf) {
            const int bk = ps * 4, slot = bk >> 4, within = bk & 15;
            *(u32*)(nb + pm * ROWB + ((slot ^ (pm & 7)) << 4) + within) =
                packh2(e.x, e.y);
        }
        __syncthreads();
    }

#pragma unroll
    for (int q = 0; q < 4; ++q) {
        const int bb = b0 + c4 * 4 + q;
        out[bb * 256 + d * 128 + hd] = rm[q];
    }
}

extern "C" void kernel_launch(void* const* d_in, const int* in_sizes, int n_in,
                              void* d_out, int out_size, void* d_ws, size_t ws_size,
                              hipStream_t stream) {
    const int*   idx   = (const int*)d_in[0];
    const float* masks = (const float*)d_in[1];
    const float* emb   = (const float*)d_in[2];
    const float* Wih_f = (const float*)d_in[3];
    const float* Whh_f = (const float*)d_in[4];
    const float* bih_f = (const float*)d_in[5];
    const float* bhh_f = (const float*)d_in[6];
    const float* Wih_b = (const float*)d_in[7];
    const float* Whh_b = (const float*)d_in[8];
    const float* bih_b = (const float*)d_in[9];
    const float* bhh_b = (const float*)d_in[10];
    float* out = (float*)d_out;

    bilstm_mfma_kernel<<<dim3(32), dim3(512), 0, stream>>>(
        idx, masks, emb,
        Wih_f, Whh_f, bih_f, bhh_f,
        Wih_b, Whh_b, bih_b, bhh_b,
        out);
}